// Round 8
// baseline (241.025 us; speedup 1.0000x reference)
//
#include <hip/hip_runtime.h>
#include <hip/hip_bf16.h>
#include <stdint.h>

typedef unsigned short u16;
typedef __attribute__((ext_vector_type(8))) __bf16 bf16x8;
typedef __attribute__((ext_vector_type(4))) short bf16x4s;
typedef __attribute__((ext_vector_type(4))) float f32x4;

#define LOG2E 1.44269504088896340736f
#define FIXED_M 16.0f   // scores (log2 domain) std~1.44 -> max < 16 over 2^27 samples

__device__ inline u16 f2bf(float f){
  uint32_t u = __float_as_uint(f);
  u += 0x7FFFu + ((u >> 16) & 1u);   // round-to-nearest-even
  return (u16)(u >> 16);
}
__device__ inline float bf2f(u16 v){
  return __uint_as_float(((uint32_t)v) << 16);
}

// v_mfma_f32_16x16x16_bf16 (gfx90a+ "_1k" builtin, valid on gfx950 per ISA §10).
// Host pass can't see AMDGCN builtins via __has_builtin -> give it a parse stub.
__device__ inline f32x4 mfma_16x16x16(bf16x4s a, bf16x4s b, f32x4 c){
#if defined(__HIP_DEVICE_COMPILE__)
  return __builtin_amdgcn_mfma_f32_16x16x16bf16_1k(a, b, c, 0, 0, 0);
#else
  (void)a; (void)b;
  return c;   // host-side parse-only stub; never executed
#endif
}

// ---------------------------------------------------------------------------
// Kernel C: W[768][64] x3 (fp32) -> wtf in EXACT MFMA B-fragment order:
// frag f (0..11), kstep (0..23): lane holds B[k=kstep*32+quad*8+j][n=f*16+n16]
// at wtf[((f*24+kstep)*64 + lane)*8 + j]. Folds (1/8)*log2e into Wq.
// ---------------------------------------------------------------------------
__global__ __launch_bounds__(256) void wt_kernel(const float* __restrict__ Wq,
                                                 const float* __restrict__ Wk,
                                                 const float* __restrict__ Wv,
                                                 u16* __restrict__ wtf){
  int idx = blockIdx.x * 256 + threadIdx.x;
  if (idx >= 192 * 768) return;
  int n = idx / 768, c = idx - n * 768;
  int h = n & 63;
  const float* W = (n < 64) ? Wq : ((n < 128) ? Wk : Wv);
  float v = W[c * 64 + h];
  if (n < 64) v *= 0.125f * LOG2E;
  int f = n >> 4, n16 = n & 15;
  int kstep = c >> 5, quad = (c >> 3) & 3, j = c & 7;
  wtf[(size_t)((f * 24 + kstep) * 64 + quad * 16 + n16) * 8 + j] = f2bf(v);
}

// ---------------------------------------------------------------------------
// Kernel A: projection GEMM v5 (unchanged from R6) — zero LDS, zero barriers,
// register-pipelined. 512 blocks x 256 thr; wave = 16 rows x 96 N x full K.
// V written transposed: vt[b][h][t].
// ---------------------------------------------------------------------------
__global__ __launch_bounds__(256, 2) void proj_kernel(const float* __restrict__ x,
                                                      const u16* __restrict__ wtf,
                                                      u16* __restrict__ qs,
                                                      u16* __restrict__ ks,
                                                      u16* __restrict__ vt){
  const int tid = threadIdx.x;
  const int w = tid >> 6, lane = tid & 63;
  const int n16 = lane & 15, quad = lane >> 4;
  const int nh = blockIdx.x & 1;
  const int rb = (blockIdx.x >> 1) * 64;
  const int row = rb + w * 16 + n16;
  const float* xr = x + (size_t)row * 768 + quad * 8;

  const f32x4 fz = {0.f, 0.f, 0.f, 0.f};
  f32x4 acc[6];
#pragma unroll
  for (int i = 0; i < 6; ++i) acc[i] = fz;

  float4 xa = *(const float4*)(xr);
  float4 xb = *(const float4*)(xr + 4);

#pragma unroll
  for (int kstep = 0; kstep < 24; ++kstep){
    float4 na, nb;
    if (kstep < 23){
      na = *(const float4*)(xr + (kstep + 1) * 32);
      nb = *(const float4*)(xr + (kstep + 1) * 32 + 4);
    }
    union { bf16x8 v; u16 e[8]; } ua;
    ua.e[0] = f2bf(xa.x); ua.e[1] = f2bf(xa.y);
    ua.e[2] = f2bf(xa.z); ua.e[3] = f2bf(xa.w);
    ua.e[4] = f2bf(xb.x); ua.e[5] = f2bf(xb.y);
    ua.e[6] = f2bf(xb.z); ua.e[7] = f2bf(xb.w);
#pragma unroll
    for (int i = 0; i < 6; ++i){
      bf16x8 bfrag = *(const bf16x8*)(wtf + (size_t)(((nh * 6 + i) * 24 + kstep) * 64 + lane) * 8);
      acc[i] = __builtin_amdgcn_mfma_f32_16x16x32_bf16(ua.v, bfrag, acc[i], 0, 0, 0);
    }
    xa = na; xb = nb;
  }

#pragma unroll
  for (int i = 0; i < 6; ++i){
    int n = nh * 96 + i * 16 + n16;
#pragma unroll
    for (int r = 0; r < 4; ++r){
      int orow = rb + w * 16 + quad * 4 + r;
      u16 val = f2bf(acc[i][r]);
      if (n < 64)       qs[(size_t)orow * 64 + n]        = val;
      else if (n < 128) ks[(size_t)orow * 64 + (n - 64)] = val;
      else {
        int bb = orow >> 12, t = orow & 4095;
        vt[((size_t)bb * 64 + (n - 128)) * 4096 + t] = val;
      }
    }
  }
}

// ---------------------------------------------------------------------------
// Kernel B: causal flash v3 — WAVE-INDEPENDENT, ZERO LDS, ZERO BARRIERS.
// Wave = (b, 32 Q-rows, 8-K-tile chunk); K/V frags read directly from
// L2-resident global. Computes S^T = K*Q^T so the 16x16 MFMA C-layout
// (row=quad*4+reg) IS the B-layout of the K=16 MFMA (k=quad*4+j):
// P^T fragments for O^T += V^T * P^T come straight from the exp2'd
// C-registers (packed pairwise) — no LDS round-trip, no cross-lane ops.
// Fixed softmax max (exact by shift-invariance). grid (b,qt,ck)=4*32*8.
// ---------------------------------------------------------------------------
__global__ __launch_bounds__(256, 3) void flash_part(const u16* __restrict__ qs,
                                                     const u16* __restrict__ ks,
                                                     const u16* __restrict__ vtg,
                                                     u16* __restrict__ Opart,
                                                     float* __restrict__ ml){
  const int b  = blockIdx.x >> 8;
  const int qt = (blockIdx.x >> 3) & 31;
  const int ck = blockIdx.x & 7;
  const int tid = threadIdx.x;
  const int w = tid >> 6, lane = tid & 63;
  const int n16 = lane & 15, quad = lane >> 4;

  const int r0 = qt * 128 + w * 32;        // wave's first Q row
  const int ktmax = 2 * qt + (w >> 1);     // last K-tile this wave touches
  const int kt0 = ck * 8;
  if (kt0 > ktmax) return;                 // wave-level early-out (no barriers)
  const int kt1 = min(ktmax, kt0 + 7);

  const size_t bo = (size_t)b * 4096 * 64;
  const u16* qb = qs + bo;
  const u16* kb = ks + bo;
  const u16* vb = vtg + bo;                // [h][4096] within batch

  // Q B-frags (B-layout: lane holds Q[m=n16][k=quad*8+j]) per m-tile
  bf16x8 qB[2][2];
#pragma unroll
  for (int mt = 0; mt < 2; ++mt){
    const u16* qp = qb + (size_t)(r0 + mt * 16 + n16) * 64 + quad * 8;
    qB[mt][0] = *(const bf16x8*)(qp);
    qB[mt][1] = *(const bf16x8*)(qp + 32);
  }

  const f32x4 fz = {0.f, 0.f, 0.f, 0.f};
  f32x4 O[2][4];                 // O^T acc: [mt][hb], C-layout (row=h, col=m)
  float rs[2] = {0.f, 0.f};      // per-lane partial row sums (col m = n16)
#pragma unroll
  for (int mt = 0; mt < 2; ++mt)
#pragma unroll
    for (int hb = 0; hb < 4; ++hb) O[mt][hb] = fz;

  for (int kt = kt0; kt <= kt1; ++kt){
    // K A-frags (A-layout: lane holds K[s=16g+n16][k=quad*8+j])
    bf16x8 kA[4][2];
#pragma unroll
    for (int g = 0; g < 4; ++g){
      const u16* kp = kb + (size_t)(kt * 64 + g * 16 + n16) * 64 + quad * 8;
      kA[g][0] = *(const bf16x8*)kp;
      kA[g][1] = *(const bf16x8*)(kp + 32);
    }
    // V^T A-frags for K=16 MFMA (lane holds V^T[h=16hb+n16][s=16g+quad*4+j])
    bf16x4s vA[4][4];            // [hb][g]
#pragma unroll
    for (int hb = 0; hb < 4; ++hb){
      const u16* vp = vb + (size_t)(hb * 16 + n16) * 4096 + kt * 64 + quad * 4;
#pragma unroll
      for (int g = 0; g < 4; ++g)
        vA[hb][g] = *(const bf16x4s*)(vp + g * 16);
    }
    const bool diag = (kt == ktmax);

#pragma unroll
    for (int mt = 0; mt < 2; ++mt){
      // S^T = K * Q^T : C-layout lane holds S^T[s=16g+quad*4+r][m=n16]
      f32x4 S[4];
#pragma unroll
      for (int g = 0; g < 4; ++g){
        f32x4 s = fz;
        s = __builtin_amdgcn_mfma_f32_16x16x32_bf16(kA[g][0], qB[mt][0], s, 0, 0, 0);
        s = __builtin_amdgcn_mfma_f32_16x16x32_bf16(kA[g][1], qB[mt][1], s, 0, 0, 0);
        S[g] = s;
      }
      const int rowm = r0 + mt * 16 + n16;
      union { bf16x4s v; uint32_t u[2]; } P[4];
#pragma unroll
      for (int g = 0; g < 4; ++g){
        float p[4];
#pragma unroll
        for (int r = 0; r < 4; ++r){
          float e = __builtin_amdgcn_exp2f(S[g][r] - FIXED_M);
          if (diag){
            int s_idx = kt * 64 + g * 16 + quad * 4 + r;
            e = (s_idx <= rowm) ? e : 0.f;
          }
          p[r] = e;
          rs[mt] += e;
        }
        P[g].u[0] = (uint32_t)f2bf(p[0]) | ((uint32_t)f2bf(p[1]) << 16);
        P[g].u[1] = (uint32_t)f2bf(p[2]) | ((uint32_t)f2bf(p[3]) << 16);
      }
      // O^T += V^T * P^T  (P C-regs ARE the B-frags of the K=16 MFMA)
#pragma unroll
      for (int g = 0; g < 4; ++g){
#pragma unroll
        for (int hb = 0; hb < 4; ++hb)
          O[mt][hb] = mfma_16x16x16(vA[hb][g], P[g].v, O[mt][hb]);
      }
    }
  }

  // row sums: lanes {m, m+16, m+32, m+48} hold disjoint s-partials for row m
#pragma unroll
  for (int mt = 0; mt < 2; ++mt){
    rs[mt] += __shfl_xor(rs[mt], 16, 64);
    rs[mt] += __shfl_xor(rs[mt], 32, 64);
  }

  // epilogue: O^T C-layout lane holds (h=16hb+quad*4+r, m=n16)
  const size_t oidx = (size_t)blockIdx.x * 8192;
#pragma unroll
  for (int mt = 0; mt < 2; ++mt){
    const int row_local = w * 32 + mt * 16 + n16;
#pragma unroll
    for (int hb = 0; hb < 4; ++hb){
      uint2 d;
      d.x = (uint32_t)f2bf(O[mt][hb][0]) | ((uint32_t)f2bf(O[mt][hb][1]) << 16);
      d.y = (uint32_t)f2bf(O[mt][hb][2]) | ((uint32_t)f2bf(O[mt][hb][3]) << 16);
      *(uint2*)(Opart + oidx + (size_t)row_local * 64 + hb * 16 + quad * 4) = d;
    }
    if (quad == 0)
      ml[(size_t)blockIdx.x * 128 + row_local] = rs[mt];
  }
}

// ---------------------------------------------------------------------------
// Kernel D: combine split-K partials (fixed max -> plain sums).
// Block = (b, qt, row-half of 64). out = sum_c O_c / sum_c l_c.
// ---------------------------------------------------------------------------
__global__ __launch_bounds__(256) void combine_kernel(const u16* __restrict__ Opart,
                                                      const float* __restrict__ ml,
                                                      float* __restrict__ out){
  const int blk = blockIdx.x;
  const int half = blk & 1;
  const int qtb = blk >> 1;            // b*32 + qt
  const int qt = qtb & 31;
  const int b = qtb >> 5;
  const int nc = ((2 * qt + 1) >> 3) + 1;
  const int t = threadIdx.x;
  const int row = t >> 2, seg = t & 3;
  const int row_local = half * 64 + row;

  float L = 0.f;
  for (int c = 0; c < nc; ++c)
    L += ml[((size_t)qtb * 8 + c) * 128 + row_local];
  const float invL = 1.0f / L;

  float acc[16];
#pragma unroll
  for (int j = 0; j < 16; ++j) acc[j] = 0.f;
  for (int c = 0; c < nc; ++c){
    const u16* p = Opart + ((size_t)qtb * 8 + c) * 8192 + (size_t)row_local * 64 + seg * 16;
    uint4 d0 = *(const uint4*)p;
    uint4 d1 = *(const uint4*)(p + 8);
    const u16* e0 = (const u16*)&d0;
    const u16* e1 = (const u16*)&d1;
#pragma unroll
    for (int j = 0; j < 8; ++j){
      acc[j]     += bf2f(e0[j]);
      acc[8 + j] += bf2f(e1[j]);
    }
  }
  float* op = out + ((size_t)b * 4096 + qt * 128 + row_local) * 64 + seg * 16;
#pragma unroll
  for (int j = 0; j < 4; ++j){
    float4 v = {acc[j*4] * invL, acc[j*4+1] * invL, acc[j*4+2] * invL, acc[j*4+3] * invL};
    *(float4*)(op + j * 4) = v;
  }
}

// ---------------------------------------------------------------------------
extern "C" void kernel_launch(void* const* d_in, const int* in_sizes, int n_in,
                              void* d_out, int out_size, void* d_ws, size_t ws_size,
                              hipStream_t stream){
  const float* x  = (const float*)d_in[0];
  const float* Wq = (const float*)d_in[1];
  const float* Wk = (const float*)d_in[2];
  const float* Wv = (const float*)d_in[3];
  float* out = (float*)d_out;

  // ws layout (u16 elems): qs | ks | vt (each 16384*64) | wtf (192*768)
  //                        | Opart (1024*8192) | ml (1024*128 f32)  ~24 MB
  u16* qs = (u16*)d_ws;
  u16* ks = qs + (size_t)16384 * 64;
  u16* vt = ks + (size_t)16384 * 64;
  u16* wtf = vt + (size_t)16384 * 64;
  u16* Opart = wtf + (size_t)192 * 768;
  float* ml = (float*)(Opart + (size_t)1024 * 8192);

  wt_kernel<<<576, 256, 0, stream>>>(Wq, Wk, Wv, wtf);
  proj_kernel<<<512, 256, 0, stream>>>(x, wtf, qs, ks, vt);
  flash_part<<<1024, 256, 0, stream>>>(qs, ks, vt, Opart, ml);
  combine_kernel<<<256, 256, 0, stream>>>(Opart, ml, out);
}

// Round 9
// 162.585 us; speedup vs baseline: 1.4825x; 1.4825x over previous
//
#include <hip/hip_runtime.h>
#include <hip/hip_bf16.h>
#include <stdint.h>

typedef unsigned short u16;
typedef __attribute__((ext_vector_type(8))) __bf16 bf16x8;
typedef __attribute__((ext_vector_type(4))) short bf16x4s;
typedef __attribute__((ext_vector_type(4))) float f32x4;

#define LOG2E 1.44269504088896340736f
#define FIXED_M 16.0f   // scores (log2 domain) std~1.44 -> max < 16 over 2^27 samples

__device__ inline u16 f2bf(float f){
  uint32_t u = __float_as_uint(f);
  u += 0x7FFFu + ((u >> 16) & 1u);   // round-to-nearest-even
  return (u16)(u >> 16);
}
__device__ inline float bf2f(u16 v){
  return __uint_as_float(((uint32_t)v) << 16);
}

// v_mfma_f32_16x16x16_bf16 (gfx90a+ "_1k" builtin, valid on gfx950 per ISA §10).
__device__ inline f32x4 mfma_16x16x16(bf16x4s a, bf16x4s b, f32x4 c){
#if defined(__HIP_DEVICE_COMPILE__)
  return __builtin_amdgcn_mfma_f32_16x16x16bf16_1k(a, b, c, 0, 0, 0);
#else
  (void)a; (void)b;
  return c;   // host-side parse-only stub; never executed
#endif
}

// ---------------------------------------------------------------------------
// FRAGMENT-ORDER GLOBAL LAYOUTS (proj writes, flash reads — we own both):
//  qf: Q B-frags.  frag (b, tt=row>>4, ks2): lane holds Q[m=tt*16+n16]
//      [k=ks2*32+quad*8+j] at qf[b*262144 + (tt*2+ks2)*512 + lane*8 + j]
//  kf: K A-frags.  frag (b, kt, g, ks2): lane holds K[s=kt*64+g*16+n16]
//      [k=ks2*32+quad*8+j] at kf[b*262144 + ((kt*4+g)*2+ks2)*512 + lane*8 + j]
//  vf: V^T A-frags (K=16 MFMA), g-pairs packed to 16B: frag (b, kt, hb, gp):
//      lane elem jj -> V^T[h=hb*16+n16][s=kt*64+(2gp+(jj>>2))*16+quad*4+(jj&3)]
//      at vf[b*262144 + ((kt*4+hb)*2+gp)*512 + lane*8 + jj]
// Every flash load = 64 lanes x 16B contiguous = one 1KB transaction.
// ---------------------------------------------------------------------------

// ---------------------------------------------------------------------------
// Kernel C: W[768][64] x3 (fp32) -> wtf in proj's B-fragment order (unchanged).
// Folds (1/8)*log2e into Wq so scores are in log2 domain.
// ---------------------------------------------------------------------------
__global__ __launch_bounds__(256) void wt_kernel(const float* __restrict__ Wq,
                                                 const float* __restrict__ Wk,
                                                 const float* __restrict__ Wv,
                                                 u16* __restrict__ wtf){
  int idx = blockIdx.x * 256 + threadIdx.x;
  if (idx >= 192 * 768) return;
  int n = idx / 768, c = idx - n * 768;
  int h = n & 63;
  const float* W = (n < 64) ? Wq : ((n < 128) ? Wk : Wv);
  float v = W[c * 64 + h];
  if (n < 64) v *= 0.125f * LOG2E;
  int f = n >> 4, n16 = n & 15;
  int kstep = c >> 5, quad = (c >> 3) & 3, j = c & 7;
  wtf[(size_t)((f * 24 + kstep) * 64 + quad * 16 + n16) * 8 + j] = f2bf(v);
}

// ---------------------------------------------------------------------------
// Kernel A: projection GEMM v5 main loop (unchanged) + FRAG-SCATTER epilogue.
// 512 blocks x 256 thr; wave = 16 rows x 96 N x full K; zero LDS/barriers.
// ---------------------------------------------------------------------------
__global__ __launch_bounds__(256, 2) void proj_kernel(const float* __restrict__ x,
                                                      const u16* __restrict__ wtf,
                                                      u16* __restrict__ qf,
                                                      u16* __restrict__ kf,
                                                      u16* __restrict__ vf){
  const int tid = threadIdx.x;
  const int w = tid >> 6, lane = tid & 63;
  const int n16 = lane & 15, quad = lane >> 4;
  const int nh = blockIdx.x & 1;
  const int rb = (blockIdx.x >> 1) * 64;
  const int row = rb + w * 16 + n16;
  const float* xr = x + (size_t)row * 768 + quad * 8;

  const f32x4 fz = {0.f, 0.f, 0.f, 0.f};
  f32x4 acc[6];
#pragma unroll
  for (int i = 0; i < 6; ++i) acc[i] = fz;

  float4 xa = *(const float4*)(xr);
  float4 xb = *(const float4*)(xr + 4);

#pragma unroll
  for (int kstep = 0; kstep < 24; ++kstep){
    float4 na, nb;
    if (kstep < 23){
      na = *(const float4*)(xr + (kstep + 1) * 32);
      nb = *(const float4*)(xr + (kstep + 1) * 32 + 4);
    }
    union { bf16x8 v; u16 e[8]; } ua;
    ua.e[0] = f2bf(xa.x); ua.e[1] = f2bf(xa.y);
    ua.e[2] = f2bf(xa.z); ua.e[3] = f2bf(xa.w);
    ua.e[4] = f2bf(xb.x); ua.e[5] = f2bf(xb.y);
    ua.e[6] = f2bf(xb.z); ua.e[7] = f2bf(xb.w);
#pragma unroll
    for (int i = 0; i < 6; ++i){
      bf16x8 bfrag = *(const bf16x8*)(wtf + (size_t)(((nh * 6 + i) * 24 + kstep) * 64 + lane) * 8);
      acc[i] = __builtin_amdgcn_mfma_f32_16x16x32_bf16(ua.v, bfrag, acc[i], 0, 0, 0);
    }
    xa = na; xb = nb;
  }

  // epilogue: C/D layout col(n)=lane&15, row(m)=quad*4+reg -> frag scatter
#pragma unroll
  for (int i = 0; i < 6; ++i){
    int n = nh * 96 + i * 16 + n16;
#pragma unroll
    for (int r = 0; r < 4; ++r){
      int orow = rb + w * 16 + quad * 4 + r;
      u16 val = f2bf(acc[i][r]);
      int bb = orow >> 12, t = orow & 4095;
      size_t base = (size_t)bb * 262144;
      if (n < 64){
        int h = n;
        int tt = t >> 4, m16 = t & 15;
        int ks2 = h >> 5, fq = (h >> 3) & 3, j = h & 7;
        qf[base + (size_t)(tt * 2 + ks2) * 512 + (fq * 16 + m16) * 8 + j] = val;
      } else if (n < 128){
        int h = n - 64;
        int kt = t >> 6, g = (t >> 4) & 3, m16 = t & 15;
        int ks2 = h >> 5, fq = (h >> 3) & 3, j = h & 7;
        kf[base + (size_t)((kt * 4 + g) * 2 + ks2) * 512 + (fq * 16 + m16) * 8 + j] = val;
      } else {
        int h = n - 128;
        int hb = h >> 4, v16 = h & 15;
        int kt = t >> 6, g = (t >> 4) & 3, qv = (t >> 2) & 3, j = t & 3;
        int gp = g >> 1, jj = (g & 1) * 4 + j;
        vf[base + (size_t)((kt * 4 + hb) * 2 + gp) * 512 + (qv * 16 + v16) * 8 + jj] = val;
      }
    }
  }
}

// ---------------------------------------------------------------------------
// Kernel B: causal flash v4 — wave-independent, zero LDS, zero barriers,
// ALL loads fragment-ordered 1KB coalesced. S^T = K*Q^T; the 16x16 C-layout
// (row=quad*4+reg) IS the K=16 MFMA B-layout (k=quad*4+j) -> P^T frags come
// straight from exp2'd C-regs. Fixed softmax max (exact by shift-invariance).
// grid (b,qt,ck)=4*32*8; long blocks (large qt) dispatched first.
// ---------------------------------------------------------------------------
__global__ __launch_bounds__(256, 3) void flash_part(const u16* __restrict__ qf,
                                                     const u16* __restrict__ kf,
                                                     const u16* __restrict__ vf,
                                                     u16* __restrict__ Opart,
                                                     float* __restrict__ ml){
  const int b  = blockIdx.x >> 8;
  const int qt = 31 - ((blockIdx.x >> 3) & 31);   // longest work first
  const int ck = blockIdx.x & 7;
  const int tid = threadIdx.x;
  const int w = tid >> 6, lane = tid & 63;
  const int n16 = lane & 15, quad = lane >> 4;

  const int r0 = qt * 128 + w * 32;        // wave's first Q row
  const int ktmax = 2 * qt + (w >> 1);     // last K-tile this wave touches
  const int kt0 = ck * 8;
  if (kt0 > ktmax) return;                 // wave-level early-out
  const int kt1 = min(ktmax, kt0 + 7);

  const size_t bo = (size_t)b * 262144;
  const int lidx = (b * 32 + qt) * 8 + ck; // logical index for Opart/ml

  // Q B-frags: one coalesced 1KB load each
  bf16x8 qB[2][2];
#pragma unroll
  for (int mt = 0; mt < 2; ++mt){
    const int tt = (r0 >> 4) + mt;
    qB[mt][0] = *(const bf16x8*)(qf + bo + (size_t)(tt * 2 + 0) * 512 + lane * 8);
    qB[mt][1] = *(const bf16x8*)(qf + bo + (size_t)(tt * 2 + 1) * 512 + lane * 8);
  }

  const f32x4 fz = {0.f, 0.f, 0.f, 0.f};
  f32x4 O[2][4];                 // O^T acc: [mt][hb], C-layout (row=h, col=m)
  float rs[2] = {0.f, 0.f};
#pragma unroll
  for (int mt = 0; mt < 2; ++mt)
#pragma unroll
    for (int hb = 0; hb < 4; ++hb) O[mt][hb] = fz;

  for (int kt = kt0; kt <= kt1; ++kt){
    // K A-frags: 8 coalesced 1KB loads
    const u16* kp = kf + bo + (size_t)(kt * 8) * 512 + lane * 8;
    bf16x8 kA[4][2];
#pragma unroll
    for (int g = 0; g < 4; ++g){
      kA[g][0] = *(const bf16x8*)(kp + (g * 2 + 0) * 512);
      kA[g][1] = *(const bf16x8*)(kp + (g * 2 + 1) * 512);
    }
    // V^T A-frags (g-pairs packed): 8 coalesced 1KB loads
    const u16* vp = vf + bo + (size_t)(kt * 8) * 512 + lane * 8;
    union { bf16x8 w8; bf16x4s h4[2]; } vload[4][2];
#pragma unroll
    for (int hb = 0; hb < 4; ++hb){
      vload[hb][0].w8 = *(const bf16x8*)(vp + (hb * 2 + 0) * 512);
      vload[hb][1].w8 = *(const bf16x8*)(vp + (hb * 2 + 1) * 512);
    }
    const bool diag = (kt == ktmax);

#pragma unroll
    for (int mt = 0; mt < 2; ++mt){
      // S^T = K * Q^T : C-layout lane holds S^T[s=16g+quad*4+r][m=n16]
      f32x4 S[4];
#pragma unroll
      for (int g = 0; g < 4; ++g){
        f32x4 s = fz;
        s = __builtin_amdgcn_mfma_f32_16x16x32_bf16(kA[g][0], qB[mt][0], s, 0, 0, 0);
        s = __builtin_amdgcn_mfma_f32_16x16x32_bf16(kA[g][1], qB[mt][1], s, 0, 0, 0);
        S[g] = s;
      }
      const int rowm = r0 + mt * 16 + n16;
      union { bf16x4s v; uint32_t u[2]; } P[4];
#pragma unroll
      for (int g = 0; g < 4; ++g){
        float p[4];
#pragma unroll
        for (int r = 0; r < 4; ++r){
          float e = __builtin_amdgcn_exp2f(S[g][r] - FIXED_M);
          if (diag){
            int s_idx = kt * 64 + g * 16 + quad * 4 + r;
            e = (s_idx <= rowm) ? e : 0.f;
          }
          p[r] = e;
          rs[mt] += e;
        }
        P[g].u[0] = (uint32_t)f2bf(p[0]) | ((uint32_t)f2bf(p[1]) << 16);
        P[g].u[1] = (uint32_t)f2bf(p[2]) | ((uint32_t)f2bf(p[3]) << 16);
      }
      // O^T += V^T * P^T  (P C-regs ARE the B-frags of the K=16 MFMA)
#pragma unroll
      for (int g = 0; g < 4; ++g){
#pragma unroll
        for (int hb = 0; hb < 4; ++hb)
          O[mt][hb] = mfma_16x16x16(vload[hb][g >> 1].h4[g & 1], P[g].v, O[mt][hb]);
      }
    }
  }

  // row sums: lanes {m, m+16, m+32, m+48} hold disjoint s-partials for row m
#pragma unroll
  for (int mt = 0; mt < 2; ++mt){
    rs[mt] += __shfl_xor(rs[mt], 16, 64);
    rs[mt] += __shfl_xor(rs[mt], 32, 64);
  }

  // epilogue: O^T C-layout lane holds (h=16hb+quad*4+r, m=n16)
  const size_t oidx = (size_t)lidx * 8192;
#pragma unroll
  for (int mt = 0; mt < 2; ++mt){
    const int row_local = w * 32 + mt * 16 + n16;
#pragma unroll
    for (int hb = 0; hb < 4; ++hb){
      uint2 d;
      d.x = (uint32_t)f2bf(O[mt][hb][0]) | ((uint32_t)f2bf(O[mt][hb][1]) << 16);
      d.y = (uint32_t)f2bf(O[mt][hb][2]) | ((uint32_t)f2bf(O[mt][hb][3]) << 16);
      *(uint2*)(Opart + oidx + (size_t)row_local * 64 + hb * 16 + quad * 4) = d;
    }
    if (quad == 0)
      ml[(size_t)lidx * 128 + row_local] = rs[mt];
  }
}

// ---------------------------------------------------------------------------
// Kernel D: combine split-K partials (fixed max -> plain sums).
// Block = (b, qt, row-half of 64). out = sum_c O_c / sum_c l_c.
// ---------------------------------------------------------------------------
__global__ __launch_bounds__(256) void combine_kernel(const u16* __restrict__ Opart,
                                                      const float* __restrict__ ml,
                                                      float* __restrict__ out){
  const int blk = blockIdx.x;
  const int half = blk & 1;
  const int qtb = blk >> 1;            // b*32 + qt
  const int qt = qtb & 31;
  const int b = qtb >> 5;
  const int nc = ((2 * qt + 1) >> 3) + 1;
  const int t = threadIdx.x;
  const int row = t >> 2, seg = t & 3;
  const int row_local = half * 64 + row;

  float L = 0.f;
  for (int c = 0; c < nc; ++c)
    L += ml[((size_t)qtb * 8 + c) * 128 + row_local];
  const float invL = 1.0f / L;

  float acc[16];
#pragma unroll
  for (int j = 0; j < 16; ++j) acc[j] = 0.f;
  for (int c = 0; c < nc; ++c){
    const u16* p = Opart + ((size_t)qtb * 8 + c) * 8192 + (size_t)row_local * 64 + seg * 16;
    uint4 d0 = *(const uint4*)p;
    uint4 d1 = *(const uint4*)(p + 8);
    const u16* e0 = (const u16*)&d0;
    const u16* e1 = (const u16*)&d1;
#pragma unroll
    for (int j = 0; j < 8; ++j){
      acc[j]     += bf2f(e0[j]);
      acc[8 + j] += bf2f(e1[j]);
    }
  }
  float* op = out + ((size_t)b * 4096 + qt * 128 + row_local) * 64 + seg * 16;
#pragma unroll
  for (int j = 0; j < 4; ++j){
    float4 v = {acc[j*4] * invL, acc[j*4+1] * invL, acc[j*4+2] * invL, acc[j*4+3] * invL};
    *(float4*)(op + j * 4) = v;
  }
}

// ---------------------------------------------------------------------------
extern "C" void kernel_launch(void* const* d_in, const int* in_sizes, int n_in,
                              void* d_out, int out_size, void* d_ws, size_t ws_size,
                              hipStream_t stream){
  const float* x  = (const float*)d_in[0];
  const float* Wq = (const float*)d_in[1];
  const float* Wk = (const float*)d_in[2];
  const float* Wv = (const float*)d_in[3];
  float* out = (float*)d_out;

  // ws layout (u16 elems): qf | kf | vf (each 4*262144) | wtf (192*768)
  //                        | Opart (1024*8192) | ml (1024*128 f32)  ~24 MB
  u16* qf = (u16*)d_ws;
  u16* kf = qf + (size_t)4 * 262144;
  u16* vf = kf + (size_t)4 * 262144;
  u16* wtf = vf + (size_t)4 * 262144;
  u16* Opart = wtf + (size_t)192 * 768;
  float* ml = (float*)(Opart + (size_t)1024 * 8192);

  wt_kernel<<<576, 256, 0, stream>>>(Wq, Wk, Wv, wtf);
  proj_kernel<<<512, 256, 0, stream>>>(x, wtf, qf, kf, vf);
  flash_part<<<1024, 256, 0, stream>>>(qf, kf, vf, Opart, ml);
  combine_kernel<<<256, 256, 0, stream>>>(Opart, ml, out);
}